// Round 2
// baseline (263.535 us; speedup 1.0000x reference)
//
#include <hip/hip_runtime.h>
#include <hip/hip_bf16.h>

// CCAM: x (16,1024,64,64), martx (4096,64), scalars aphal/gamma (=1.0).
// rows = B*C = 16384, N = 4096 spatial, KDIM = 64.
// energy[r][k] = sum_n x[r][n] * M[n][k]           (GEMM1, K=4096)
// att = softmax(alpha * (rowmax(energy) - energy))  (64-wide)
// out[r][n] = gamma * sum_k att[r][k]*M[n][k] + x[r][n]
//
// Device dtype (bf16 vs fp32) is detected at runtime from aphal==1.0:
// bf16 -> first ushort 0x3F80 ; fp32 -> first uint 0x3F800000 (low ushort 0).

using frag_ab = __attribute__((ext_vector_type(8))) short;   // 8 bf16 = 4 VGPR
using f32x4   = __attribute__((ext_vector_type(4))) float;   // MFMA C/D

#define MFMA16(a, b, c) __builtin_amdgcn_mfma_f32_16x16x32_bf16((a), (b), (c), 0, 0, 0)

static __device__ __forceinline__ unsigned short f2bf_bits(float f) {
    __hip_bfloat16 h = __float2bfloat16(f);
    return *reinterpret_cast<const unsigned short*>(&h);
}
static __device__ __forceinline__ frag_ab load_frag(const __hip_bfloat16* p) {
    return *reinterpret_cast<const frag_ab*>(p);
}
static __device__ __forceinline__ frag_ab cvt_frag(const float* p) {
    float4 a = *reinterpret_cast<const float4*>(p);
    float4 b = *reinterpret_cast<const float4*>(p + 4);
    frag_ab r;
    r[0] = (short)f2bf_bits(a.x); r[1] = (short)f2bf_bits(a.y);
    r[2] = (short)f2bf_bits(a.z); r[3] = (short)f2bf_bits(a.w);
    r[4] = (short)f2bf_bits(b.x); r[5] = (short)f2bf_bits(b.y);
    r[6] = (short)f2bf_bits(b.z); r[7] = (short)f2bf_bits(b.w);
    return r;
}

// ---------------- kernel 0: canonicalize martx -> Mt (64x4096 bf16) + Mbf (4096x64 bf16) ----------
__global__ __launch_bounds__(256) void prep_martx(
        const void* __restrict__ Mraw, const void* __restrict__ aphal,
        __hip_bfloat16* __restrict__ Mt, __hip_bfloat16* __restrict__ Mbf) {
    const bool isbf = ((*(const unsigned*)aphal) & 0xFFFFu) == 0x3F80u;
    __shared__ __hip_bfloat16 tile[64][65];
    const int t  = threadIdx.x;
    const int nb = blockIdx.x * 64;
#pragma unroll
    for (int i = 0; i < 16; ++i) {
        const int r = (t >> 6) + i * 4;   // 0..63 (n within this 64-row band)
        const int k = t & 63;             // coalesced along k
        unsigned short bits;
        if (isbf) bits = ((const unsigned short*)Mraw)[(size_t)(nb + r) * 64 + k];
        else      bits = f2bf_bits(((const float*)Mraw)[(size_t)(nb + r) * 64 + k]);
        __hip_bfloat16 h = *reinterpret_cast<__hip_bfloat16*>(&bits);
        tile[r][k] = h;
        Mbf[(size_t)(nb + r) * 64 + k] = h;
    }
    __syncthreads();
#pragma unroll
    for (int i = 0; i < 16; ++i) {
        const int k = (t >> 6) + i * 4;
        const int n = t & 63;             // coalesced along n
        Mt[(size_t)k * 4096 + nb + n] = tile[n][k];
    }
}

// ---------------- kernel 1: fused CCAM ----------------
__global__ __launch_bounds__(256, 4) void ccam_main(
        const void* __restrict__ x,
        const __hip_bfloat16* __restrict__ Mt,   // (64,4096) k-major bf16
        const __hip_bfloat16* __restrict__ Mbf,  // (4096,64) n-major bf16
        const void* __restrict__ aphal,
        const void* __restrict__ gamma,
        void* __restrict__ out) {
    __shared__ __align__(16) float Ep[4][16][68];    // phase-1 partials, padded stride
    __shared__ __align__(16) float outS[4][16][68];  // per-wave epilogue stage

    const int tid  = threadIdx.x;
    const int w    = tid >> 6;        // wave 0..3
    const int lane = tid & 63;
    const int g    = lane >> 4;       // k-group 0..3
    const int r15  = lane & 15;
    const int rowbase = blockIdx.x * 16;

    const unsigned au = *(const unsigned*)aphal;
    const unsigned gu = *(const unsigned*)gamma;
    const bool isbf = (au & 0xFFFFu) == 0x3F80u;
    const float alpha = isbf ? __uint_as_float((au & 0xFFFFu) << 16) : __uint_as_float(au);
    const float gam   = isbf ? __uint_as_float((gu & 0xFFFFu) << 16) : __uint_as_float(gu);

    // ============ Phase 1: energy partials, wave covers contraction n in [w*1024, w*1024+1024) ====
    f32x4 acc0 = {0.f, 0.f, 0.f, 0.f};
    f32x4 acc1 = acc0, acc2 = acc0, acc3 = acc0;
    {
        const int kb0 = w * 1024;
        const size_t xofs = (size_t)(rowbase + r15) * 4096 + kb0 + 8 * g;
        const __hip_bfloat16* mt0 = Mt + (size_t)r15 * 4096 + kb0 + 8 * g;
        if (isbf) {
            const __hip_bfloat16* xr = (const __hip_bfloat16*)x + xofs;
#pragma unroll 4
            for (int s = 0; s < 32; ++s) {
                frag_ab a  = load_frag(xr  + s * 32);
                frag_ab b0 = load_frag(mt0 + s * 32);
                frag_ab b1 = load_frag(mt0 + 16 * 4096 + s * 32);
                frag_ab b2 = load_frag(mt0 + 32 * 4096 + s * 32);
                frag_ab b3 = load_frag(mt0 + 48 * 4096 + s * 32);
                acc0 = MFMA16(a, b0, acc0);
                acc1 = MFMA16(a, b1, acc1);
                acc2 = MFMA16(a, b2, acc2);
                acc3 = MFMA16(a, b3, acc3);
            }
        } else {
            const float* xr = (const float*)x + xofs;
#pragma unroll 4
            for (int s = 0; s < 32; ++s) {
                frag_ab a  = cvt_frag(xr + s * 32);
                frag_ab b0 = load_frag(mt0 + s * 32);
                frag_ab b1 = load_frag(mt0 + 16 * 4096 + s * 32);
                frag_ab b2 = load_frag(mt0 + 32 * 4096 + s * 32);
                frag_ab b3 = load_frag(mt0 + 48 * 4096 + s * 32);
                acc0 = MFMA16(a, b0, acc0);
                acc1 = MFMA16(a, b1, acc1);
                acc2 = MFMA16(a, b2, acc2);
                acc3 = MFMA16(a, b3, acc3);
            }
        }
    }
    // D layout (measured m89/m91): col = lane&15 (kdim-in-tile), row = 4*(lane>>4)+reg (channel)
#pragma unroll
    for (int r = 0; r < 4; ++r) {
        Ep[w][4 * g + r][ 0 + r15] = acc0[r];
        Ep[w][4 * g + r][16 + r15] = acc1[r];
        Ep[w][4 * g + r][32 + r15] = acc2[r];
        Ep[w][4 * g + r][48 + r15] = acc3[r];
    }
    __syncthreads();

    // ============ Phase 2: softmax (each wave redundantly, straight into A-frag layout) ==========
    // lane holds energy for channel-row r15 at kdims {8g+j} (e[0..7]) and {32+8g+j} (e[8..15])
    float e[16];
#pragma unroll
    for (int j = 0; j < 16; ++j) e[j] = 0.f;
#pragma unroll
    for (int p = 0; p < 4; ++p) {
        float4 lo  = *reinterpret_cast<const float4*>(&Ep[p][r15][8 * g]);
        float4 lo2 = *reinterpret_cast<const float4*>(&Ep[p][r15][8 * g + 4]);
        float4 hi  = *reinterpret_cast<const float4*>(&Ep[p][r15][32 + 8 * g]);
        float4 hi2 = *reinterpret_cast<const float4*>(&Ep[p][r15][32 + 8 * g + 4]);
        e[0] += lo.x;  e[1] += lo.y;  e[2]  += lo.z;  e[3]  += lo.w;
        e[4] += lo2.x; e[5] += lo2.y; e[6]  += lo2.z; e[7]  += lo2.w;
        e[8] += hi.x;  e[9] += hi.y;  e[10] += hi.z;  e[11] += hi.w;
        e[12] += hi2.x; e[13] += hi2.y; e[14] += hi2.z; e[15] += hi2.w;
    }
    float m = e[0];
#pragma unroll
    for (int j = 1; j < 16; ++j) m = fmaxf(m, e[j]);
    m = fmaxf(m, __shfl_xor(m, 16, 64));
    m = fmaxf(m, __shfl_xor(m, 32, 64));
    float v[16];
#pragma unroll
    for (int j = 0; j < 16; ++j) v[j] = alpha * (m - e[j]);
    float vm = v[0];
#pragma unroll
    for (int j = 1; j < 16; ++j) vm = fmaxf(vm, v[j]);
    vm = fmaxf(vm, __shfl_xor(vm, 16, 64));
    vm = fmaxf(vm, __shfl_xor(vm, 32, 64));
    float pj[16];
    float s = 0.f;
#pragma unroll
    for (int j = 0; j < 16; ++j) { pj[j] = __expf(v[j] - vm); s += pj[j]; }
    s += __shfl_xor(s, 16, 64);
    s += __shfl_xor(s, 32, 64);
    const float inv = 1.f / s;
    frag_ab A0, A1;   // att A-frags: row = r15 (channel), k = 8g+j (A0) / 32+8g+j (A1)
#pragma unroll
    for (int j = 0; j < 8; ++j) {
        A0[j] = (short)f2bf_bits(pj[j] * inv);
        A1[j] = (short)f2bf_bits(pj[8 + j] * inv);
    }

    // ============ Phase 3: out = gamma * (att @ M^T) + x, wave covers n in [w*1024, ...) =========
    const int nb0 = w * 1024;
    for (int grp = 0; grp < 16; ++grp) {
        const int nbase = nb0 + grp * 64;
        // B[k][n]: n = 16t + r15 (spatial), k = 8g+j (+32) -> Mbf[n][k] contiguous 16B
        const __hip_bfloat16* mrow = Mbf + (size_t)(nbase + r15) * 64 + 8 * g;
        frag_ab b00 = load_frag(mrow);
        frag_ab b01 = load_frag(mrow + 32);
        frag_ab b10 = load_frag(mrow + 16 * 64);
        frag_ab b11 = load_frag(mrow + 16 * 64 + 32);
        frag_ab b20 = load_frag(mrow + 32 * 64);
        frag_ab b21 = load_frag(mrow + 32 * 64 + 32);
        frag_ab b30 = load_frag(mrow + 48 * 64);
        frag_ab b31 = load_frag(mrow + 48 * 64 + 32);
        f32x4 d0 = {0.f, 0.f, 0.f, 0.f};
        f32x4 d1 = d0, d2 = d0, d3 = d0;
        d0 = MFMA16(A0, b00, d0); d0 = MFMA16(A1, b01, d0);
        d1 = MFMA16(A0, b10, d1); d1 = MFMA16(A1, b11, d1);
        d2 = MFMA16(A0, b20, d2); d2 = MFMA16(A1, b21, d2);
        d3 = MFMA16(A0, b30, d3); d3 = MFMA16(A1, b31, d3);

        // WAR: prior group's LDS reads must complete before overwrite
        asm volatile("s_waitcnt lgkmcnt(0)" ::: "memory");
        __builtin_amdgcn_sched_barrier(0);
#pragma unroll
        for (int r = 0; r < 4; ++r) {
            outS[w][4 * g + r][ 0 + r15] = d0[r];
            outS[w][4 * g + r][16 + r15] = d1[r];
            outS[w][4 * g + r][32 + r15] = d2[r];
            outS[w][4 * g + r][48 + r15] = d3[r];
        }
        // RAW: cross-lane visibility within the wave
        asm volatile("s_waitcnt lgkmcnt(0)" ::: "memory");
        __builtin_amdgcn_sched_barrier(0);

        // epilogue: lane covers row rr = lane>>2, 16 contiguous cols at cb = (lane&3)*16
        const int rr = lane >> 2;
        const int cb = (lane & 3) * 16;
        float4 o0 = *reinterpret_cast<const float4*>(&outS[w][rr][cb + 0]);
        float4 o1 = *reinterpret_cast<const float4*>(&outS[w][rr][cb + 4]);
        float4 o2 = *reinterpret_cast<const float4*>(&outS[w][rr][cb + 8]);
        float4 o3 = *reinterpret_cast<const float4*>(&outS[w][rr][cb + 12]);
        float oc[16] = {o0.x, o0.y, o0.z, o0.w, o1.x, o1.y, o1.z, o1.w,
                        o2.x, o2.y, o2.z, o2.w, o3.x, o3.y, o3.z, o3.w};

        const size_t gofs = (size_t)(rowbase + rr) * 4096 + nbase + cb;
        if (isbf) {
            const __hip_bfloat16* xp = (const __hip_bfloat16*)x + gofs;
            uint4 xa = *reinterpret_cast<const uint4*>(xp);
            uint4 xb = *reinterpret_cast<const uint4*>(xp + 8);
            unsigned xu[8] = {xa.x, xa.y, xa.z, xa.w, xb.x, xb.y, xb.z, xb.w};
            unsigned ru[8];
#pragma unroll
            for (int i = 0; i < 8; ++i) {
                float xlo = __uint_as_float((xu[i] & 0xFFFFu) << 16);
                float xhi = __uint_as_float(xu[i] & 0xFFFF0000u);
                float ylo = gam * oc[2 * i]     + xlo;
                float yhi = gam * oc[2 * i + 1] + xhi;
                ru[i] = (unsigned)f2bf_bits(ylo) | ((unsigned)f2bf_bits(yhi) << 16);
            }
            __hip_bfloat16* op = (__hip_bfloat16*)out + gofs;
            *reinterpret_cast<uint4*>(op)     = make_uint4(ru[0], ru[1], ru[2], ru[3]);
            *reinterpret_cast<uint4*>(op + 8) = make_uint4(ru[4], ru[5], ru[6], ru[7]);
        } else {
            const float* xp = (const float*)x + gofs;
            float* op = (float*)out + gofs;
#pragma unroll
            for (int q = 0; q < 4; ++q) {
                float4 xv = *reinterpret_cast<const float4*>(xp + 4 * q);
                float4 yv;
                yv.x = gam * oc[4 * q + 0] + xv.x;
                yv.y = gam * oc[4 * q + 1] + xv.y;
                yv.z = gam * oc[4 * q + 2] + xv.z;
                yv.w = gam * oc[4 * q + 3] + xv.w;
                *reinterpret_cast<float4*>(op + 4 * q) = yv;
            }
        }
    }
}

extern "C" void kernel_launch(void* const* d_in, const int* in_sizes, int n_in,
                              void* d_out, int out_size, void* d_ws, size_t ws_size,
                              hipStream_t stream) {
    const void* x     = d_in[0];
    const void* M     = d_in[1];
    const void* aphal = d_in[2];
    const void* gamma = d_in[3];
    __hip_bfloat16* Mt  = (__hip_bfloat16*)d_ws;                  // 64*4096*2   = 512 KB
    __hip_bfloat16* Mbf = (__hip_bfloat16*)d_ws + 64 * 4096;      // 4096*64*2   = 512 KB

    hipLaunchKernelGGL(prep_martx, dim3(64), dim3(256), 0, stream, M, aphal, Mt, Mbf);
    hipLaunchKernelGGL(ccam_main, dim3(1024), dim3(256), 0, stream,
                       x, Mt, Mbf, aphal, gamma, d_out);
}

// Round 3
// 261.567 us; speedup vs baseline: 1.0075x; 1.0075x over previous
//
#include <hip/hip_runtime.h>
#include <hip/hip_bf16.h>

// CCAM (fp32 in/out, confirmed round 2): x (16,1024,64,64), martx (4096,64).
// rows = B*C = 16384, N = 4096 spatial, KDIM = 64.
// energy[r][k] = sum_n x[r][n] * M[n][k]           (GEMM1, K=4096)
// att = softmax(alpha * (rowmax(energy) - energy))  (64-wide)
// out[r][n] = gamma * sum_k att[r][k]*M[n][k] + x[r][n]
//   -> computed as (gamma*att) @ M^T with MFMA C initialized to x (residual fold).

using frag_ab = __attribute__((ext_vector_type(8))) short;   // 8 bf16 = 4 VGPR
using f32x4   = __attribute__((ext_vector_type(4))) float;   // MFMA C/D

#define MFMA16(a, b, c) __builtin_amdgcn_mfma_f32_16x16x32_bf16((a), (b), (c), 0, 0, 0)

static __device__ __forceinline__ unsigned short f2bf_bits(float f) {
    __hip_bfloat16 h = __float2bfloat16(f);
    return *reinterpret_cast<const unsigned short*>(&h);
}
static __device__ __forceinline__ frag_ab load_frag(const __hip_bfloat16* p) {
    return *reinterpret_cast<const frag_ab*>(p);
}
static __device__ __forceinline__ frag_ab cvt2(float4 a, float4 b) {
    frag_ab r;
    r[0] = (short)f2bf_bits(a.x); r[1] = (short)f2bf_bits(a.y);
    r[2] = (short)f2bf_bits(a.z); r[3] = (short)f2bf_bits(a.w);
    r[4] = (short)f2bf_bits(b.x); r[5] = (short)f2bf_bits(b.y);
    r[6] = (short)f2bf_bits(b.z); r[7] = (short)f2bf_bits(b.w);
    return r;
}

// ------------- kernel 0: martx fp32 -> Mt (64x4096 bf16, k-major) + Mbf (4096x64 bf16) -------------
__global__ __launch_bounds__(256) void prep_martx(
        const float* __restrict__ M,
        __hip_bfloat16* __restrict__ Mt, __hip_bfloat16* __restrict__ Mbf) {
    __shared__ __hip_bfloat16 tile[64][65];
    const int t  = threadIdx.x;
    const int nb = blockIdx.x * 64;
#pragma unroll
    for (int i = 0; i < 16; ++i) {
        const int r = (t >> 6) + i * 4;   // n within band
        const int k = t & 63;
        unsigned short bits = f2bf_bits(M[(size_t)(nb + r) * 64 + k]);
        __hip_bfloat16 h = *reinterpret_cast<__hip_bfloat16*>(&bits);
        tile[r][k] = h;
        Mbf[(size_t)(nb + r) * 64 + k] = h;
    }
    __syncthreads();
#pragma unroll
    for (int i = 0; i < 16; ++i) {
        const int k = (t >> 6) + i * 4;
        const int n = t & 63;
        Mt[(size_t)k * 4096 + nb + n] = tile[n][k];
    }
}

// ---------------- kernel 1: fused CCAM ----------------
__global__ __launch_bounds__(256, 4) void ccam_main(
        const float* __restrict__ x,
        const __hip_bfloat16* __restrict__ Mt,   // (64,4096) k-major bf16
        const __hip_bfloat16* __restrict__ Mbf,  // (4096,64) n-major bf16
        const float* __restrict__ aphal,
        const float* __restrict__ gamma,
        float* __restrict__ out) {
    __shared__ __align__(16) float Ep[4][16][68];    // phase-1 partials, padded stride

    const int tid  = threadIdx.x;
    const int w    = tid >> 6;        // wave 0..3
    const int lane = tid & 63;
    const int g    = lane >> 4;       // 0..3
    const int r15  = lane & 15;
    const int rowbase = blockIdx.x * 16;

    const float alpha = aphal[0];
    const float gam   = gamma[0];

    // ===== Phase 1: energy partials; wave covers contraction n in [w*1024, w*1024+1024) =====
    f32x4 acc0 = {0.f, 0.f, 0.f, 0.f};
    f32x4 acc1 = acc0, acc2 = acc0, acc3 = acc0;
    {
        const int kb0 = w * 1024;
        const float* xr = x + (size_t)(rowbase + r15) * 4096 + kb0 + 8 * g;
        const __hip_bfloat16* mt0 = Mt + (size_t)r15 * 4096 + kb0 + 8 * g;

        // 2-stage register double-buffer (all names static; rule #20)
        float4 xA0, xA1, xB0, xB1;
        frag_ab bA0, bA1, bA2, bA3, bB0, bB1, bB2, bB3;

        xA0 = *reinterpret_cast<const float4*>(xr);
        xA1 = *reinterpret_cast<const float4*>(xr + 4);
        bA0 = load_frag(mt0);
        bA1 = load_frag(mt0 + 16 * 4096);
        bA2 = load_frag(mt0 + 32 * 4096);
        bA3 = load_frag(mt0 + 48 * 4096);

        for (int s = 0; s < 32; s += 2) {
            const int o1 = (s + 1) * 32;
            xB0 = *reinterpret_cast<const float4*>(xr + o1);
            xB1 = *reinterpret_cast<const float4*>(xr + o1 + 4);
            bB0 = load_frag(mt0 + o1);
            bB1 = load_frag(mt0 + 16 * 4096 + o1);
            bB2 = load_frag(mt0 + 32 * 4096 + o1);
            bB3 = load_frag(mt0 + 48 * 4096 + o1);

            frag_ab a = cvt2(xA0, xA1);
            acc0 = MFMA16(a, bA0, acc0);
            acc1 = MFMA16(a, bA1, acc1);
            acc2 = MFMA16(a, bA2, acc2);
            acc3 = MFMA16(a, bA3, acc3);

            if (s < 30) {
                const int o2 = (s + 2) * 32;
                xA0 = *reinterpret_cast<const float4*>(xr + o2);
                xA1 = *reinterpret_cast<const float4*>(xr + o2 + 4);
                bA0 = load_frag(mt0 + o2);
                bA1 = load_frag(mt0 + 16 * 4096 + o2);
                bA2 = load_frag(mt0 + 32 * 4096 + o2);
                bA3 = load_frag(mt0 + 48 * 4096 + o2);
            }

            frag_ab ab = cvt2(xB0, xB1);
            acc0 = MFMA16(ab, bB0, acc0);
            acc1 = MFMA16(ab, bB1, acc1);
            acc2 = MFMA16(ab, bB2, acc2);
            acc3 = MFMA16(ab, bB3, acc3);
        }
    }
    // D layout: col = lane&15 (kdim-in-tile), row = 4*(lane>>4)+reg (channel)
#pragma unroll
    for (int r = 0; r < 4; ++r) {
        Ep[w][4 * g + r][ 0 + r15] = acc0[r];
        Ep[w][4 * g + r][16 + r15] = acc1[r];
        Ep[w][4 * g + r][32 + r15] = acc2[r];
        Ep[w][4 * g + r][48 + r15] = acc3[r];
    }
    __syncthreads();

    // ===== Phase 2: softmax (each wave redundantly, straight into A-frag layout) =====
    // lane holds energy for channel-row r15 at kdims {8g+j} (e[0..7]) and {32+8g+j} (e[8..15])
    float e[16];
#pragma unroll
    for (int j = 0; j < 16; ++j) e[j] = 0.f;
#pragma unroll
    for (int p = 0; p < 4; ++p) {
        float4 lo  = *reinterpret_cast<const float4*>(&Ep[p][r15][8 * g]);
        float4 lo2 = *reinterpret_cast<const float4*>(&Ep[p][r15][8 * g + 4]);
        float4 hi  = *reinterpret_cast<const float4*>(&Ep[p][r15][32 + 8 * g]);
        float4 hi2 = *reinterpret_cast<const float4*>(&Ep[p][r15][32 + 8 * g + 4]);
        e[0] += lo.x;  e[1] += lo.y;  e[2]  += lo.z;  e[3]  += lo.w;
        e[4] += lo2.x; e[5] += lo2.y; e[6]  += lo2.z; e[7]  += lo2.w;
        e[8] += hi.x;  e[9] += hi.y;  e[10] += hi.z;  e[11] += hi.w;
        e[12] += hi2.x; e[13] += hi2.y; e[14] += hi2.z; e[15] += hi2.w;
    }
    float m = e[0];
#pragma unroll
    for (int j = 1; j < 16; ++j) m = fmaxf(m, e[j]);
    m = fmaxf(m, __shfl_xor(m, 16, 64));
    m = fmaxf(m, __shfl_xor(m, 32, 64));
    float v[16];
#pragma unroll
    for (int j = 0; j < 16; ++j) v[j] = alpha * (m - e[j]);
    float vm = v[0];
#pragma unroll
    for (int j = 1; j < 16; ++j) vm = fmaxf(vm, v[j]);
    vm = fmaxf(vm, __shfl_xor(vm, 16, 64));
    vm = fmaxf(vm, __shfl_xor(vm, 32, 64));
    float pj[16];
    float s = 0.f;
#pragma unroll
    for (int j = 0; j < 16; ++j) { pj[j] = __expf(v[j] - vm); s += pj[j]; }
    s += __shfl_xor(s, 16, 64);
    s += __shfl_xor(s, 32, 64);
    const float sc = gam / s;                 // fold gamma into attention
    frag_ab A0, A1;   // A-frags: row = r15 (channel), k = 8g+j (A0) / 32+8g+j (A1)
#pragma unroll
    for (int j = 0; j < 8; ++j) {
        A0[j] = (short)f2bf_bits(pj[j] * sc);
        A1[j] = (short)f2bf_bits(pj[8 + j] * sc);
    }

    // ===== Phase 3: out = (gam*att) @ M^T + x ; wave covers n in [w*1024, (w+1)*1024) =====
    // MFMA D layout direct: element (q,r) of d_q -> out[rowbase+4g+r][nbase+16q+r15].
    const int nb0 = w * 1024;
    const float* xrow = x   + (size_t)(rowbase + 4 * g) * 4096 + r15;
    float*       orow = out + (size_t)(rowbase + 4 * g) * 4096 + r15;

    float xpA[16], xpB[16];   // [r*4+q], static indices via full unroll
#pragma unroll
    for (int r = 0; r < 4; ++r)
#pragma unroll
        for (int q = 0; q < 4; ++q)
            xpA[r * 4 + q] = xrow[(size_t)r * 4096 + nb0 + q * 16];

    for (int grp = 0; grp < 16; grp += 2) {
        // ---------- stage A: grp ----------
        {
            const int nbase = nb0 + grp * 64;
            const __hip_bfloat16* mrow = Mbf + (size_t)(nbase + r15) * 64 + 8 * g;
            frag_ab b00 = load_frag(mrow);
            frag_ab b01 = load_frag(mrow + 32);
            frag_ab b10 = load_frag(mrow + 16 * 64);
            frag_ab b11 = load_frag(mrow + 16 * 64 + 32);
            frag_ab b20 = load_frag(mrow + 32 * 64);
            frag_ab b21 = load_frag(mrow + 32 * 64 + 32);
            frag_ab b30 = load_frag(mrow + 48 * 64);
            frag_ab b31 = load_frag(mrow + 48 * 64 + 32);
            // prefetch next grp's residual (L3 stream) while MFMAs run
            const int nbn = nb0 + (grp + 1) * 64;
#pragma unroll
            for (int r = 0; r < 4; ++r)
#pragma unroll
                for (int q = 0; q < 4; ++q)
                    xpB[r * 4 + q] = xrow[(size_t)r * 4096 + nbn + q * 16];

            f32x4 d0 = {xpA[0], xpA[4], xpA[8],  xpA[12]};
            f32x4 d1 = {xpA[1], xpA[5], xpA[9],  xpA[13]};
            f32x4 d2 = {xpA[2], xpA[6], xpA[10], xpA[14]};
            f32x4 d3 = {xpA[3], xpA[7], xpA[11], xpA[15]};
            d0 = MFMA16(A0, b00, d0); d0 = MFMA16(A1, b01, d0);
            d1 = MFMA16(A0, b10, d1); d1 = MFMA16(A1, b11, d1);
            d2 = MFMA16(A0, b20, d2); d2 = MFMA16(A1, b21, d2);
            d3 = MFMA16(A0, b30, d3); d3 = MFMA16(A1, b31, d3);
#pragma unroll
            for (int r = 0; r < 4; ++r) {
                orow[(size_t)r * 4096 + nbase +  0] = d0[r];
                orow[(size_t)r * 4096 + nbase + 16] = d1[r];
                orow[(size_t)r * 4096 + nbase + 32] = d2[r];
                orow[(size_t)r * 4096 + nbase + 48] = d3[r];
            }
        }
        // ---------- stage B: grp+1 ----------
        {
            const int nbase = nb0 + (grp + 1) * 64;
            const __hip_bfloat16* mrow = Mbf + (size_t)(nbase + r15) * 64 + 8 * g;
            frag_ab b00 = load_frag(mrow);
            frag_ab b01 = load_frag(mrow + 32);
            frag_ab b10 = load_frag(mrow + 16 * 64);
            frag_ab b11 = load_frag(mrow + 16 * 64 + 32);
            frag_ab b20 = load_frag(mrow + 32 * 64);
            frag_ab b21 = load_frag(mrow + 32 * 64 + 32);
            frag_ab b30 = load_frag(mrow + 48 * 64);
            frag_ab b31 = load_frag(mrow + 48 * 64 + 32);
            if (grp < 14) {
                const int nbn = nb0 + (grp + 2) * 64;
#pragma unroll
                for (int r = 0; r < 4; ++r)
#pragma unroll
                    for (int q = 0; q < 4; ++q)
                        xpA[r * 4 + q] = xrow[(size_t)r * 4096 + nbn + q * 16];
            }
            f32x4 d0 = {xpB[0], xpB[4], xpB[8],  xpB[12]};
            f32x4 d1 = {xpB[1], xpB[5], xpB[9],  xpB[13]};
            f32x4 d2 = {xpB[2], xpB[6], xpB[10], xpB[14]};
            f32x4 d3 = {xpB[3], xpB[7], xpB[11], xpB[15]};
            d0 = MFMA16(A0, b00, d0); d0 = MFMA16(A1, b01, d0);
            d1 = MFMA16(A0, b10, d1); d1 = MFMA16(A1, b11, d1);
            d2 = MFMA16(A0, b20, d2); d2 = MFMA16(A1, b21, d2);
            d3 = MFMA16(A0, b30, d3); d3 = MFMA16(A1, b31, d3);
#pragma unroll
            for (int r = 0; r < 4; ++r) {
                orow[(size_t)r * 4096 + nbase +  0] = d0[r];
                orow[(size_t)r * 4096 + nbase + 16] = d1[r];
                orow[(size_t)r * 4096 + nbase + 32] = d2[r];
                orow[(size_t)r * 4096 + nbase + 48] = d3[r];
            }
        }
    }
}

extern "C" void kernel_launch(void* const* d_in, const int* in_sizes, int n_in,
                              void* d_out, int out_size, void* d_ws, size_t ws_size,
                              hipStream_t stream) {
    const float* x     = (const float*)d_in[0];
    const float* M     = (const float*)d_in[1];
    const float* aphal = (const float*)d_in[2];
    const float* gamma = (const float*)d_in[3];
    __hip_bfloat16* Mt  = (__hip_bfloat16*)d_ws;                  // 512 KB
    __hip_bfloat16* Mbf = (__hip_bfloat16*)d_ws + 64 * 4096;      // 512 KB

    hipLaunchKernelGGL(prep_martx, dim3(64), dim3(256), 0, stream, M, Mt, Mbf);
    hipLaunchKernelGGL(ccam_main, dim3(1024), dim3(256), 0, stream,
                       x, Mt, Mbf, aphal, gamma, (float*)d_out);
}

// Round 4
// 194.455 us; speedup vs baseline: 1.3552x; 1.3451x over previous
//
#include <hip/hip_runtime.h>
#include <hip/hip_bf16.h>

// CCAM (fp32 in/out, confirmed round 2): x (16,1024,64,64), martx (4096,64).
// rows = B*C = 16384, N = 4096 spatial, KDIM = 64.
// energy[r][k] = sum_n x[r][n] * M[n][k]           (GEMM1, K=4096)
// att = softmax(alpha * (rowmax(energy) - energy))  (64-wide)
// out[r][n] = gamma * sum_k att[r][k]*M[n][k] + x[r][n]
//
// Round-4 theory: prior kernels were stuck at ~2 TB/s because every vector
// load touched 16 scattered rows (16 cache lines / instr) -> per-CU miss-slot
// (MSHR) saturation -> ~4-8 KB in flight/CU. This version makes EVERY global
// access contiguous per instruction:
//   - x staged via global_load_lds (1 KB row-contiguous DMA, width 16)
//   - B matrices pre-permuted into frag-linear layout (1 KB contiguous/frag)
//   - phase-3 residual staged via width-4 DMA (256 B row-contiguous)

using frag_ab = __attribute__((ext_vector_type(8))) short;   // 8 bf16 = 4 VGPR
using f32x4   = __attribute__((ext_vector_type(4))) float;   // MFMA C/D

#define MFMA16(a, b, c) __builtin_amdgcn_mfma_f32_16x16x32_bf16((a), (b), (c), 0, 0, 0)
#define AS1(p) ((const __attribute__((address_space(1))) void*)(p))
#define AS3(p) ((__attribute__((address_space(3))) void*)(p))

static __device__ __forceinline__ unsigned short f2bf_bits(float f) {
    __hip_bfloat16 h = __float2bfloat16(f);
    return *reinterpret_cast<const unsigned short*>(&h);
}
static __device__ __forceinline__ frag_ab load_frag(const __hip_bfloat16* p) {
    return *reinterpret_cast<const frag_ab*>(p);
}
static __device__ __forceinline__ frag_ab cvt2(float4 a, float4 b) {
    frag_ab r;
    r[0] = (short)f2bf_bits(a.x); r[1] = (short)f2bf_bits(a.y);
    r[2] = (short)f2bf_bits(a.z); r[3] = (short)f2bf_bits(a.w);
    r[4] = (short)f2bf_bits(b.x); r[5] = (short)f2bf_bits(b.y);
    r[6] = (short)f2bf_bits(b.z); r[7] = (short)f2bf_bits(b.w);
    return r;
}

// -------- kernel 0: build frag-linear B banks -------------------------------
// MtF  (512 frags x 1 KB): frag f = gks*4+t, elem (lane,j) = M[32*gks+8g+j][16t+r15]
// MbfF (512 frags x 1 KB): frag f = nt*2+h,  elem (lane,j) = M[16nt+r15][32h+8g+j]
__global__ __launch_bounds__(256) void prep_frags(
        const float* __restrict__ M,
        __hip_bfloat16* __restrict__ MtF, __hip_bfloat16* __restrict__ MbfF) {
    const int w    = threadIdx.x >> 6;
    const int lane = threadIdx.x & 63;
    const int g    = lane >> 4;
    const int r15  = lane & 15;
    const int f    = blockIdx.x * 4 + w;    // 0..1023
    if (f < 512) {
        const int gks = f >> 2, t = f & 3;
        frag_ab fr;
#pragma unroll
        for (int j = 0; j < 8; ++j)
            fr[j] = (short)f2bf_bits(M[(size_t)(32 * gks + 8 * g + j) * 64 + 16 * t + r15]);
        *reinterpret_cast<frag_ab*>(MtF + ((size_t)f * 64 + lane) * 8) = fr;
    } else {
        const int f2 = f - 512;
        const float* src = M + (size_t)(16 * (f2 >> 1) + r15) * 64 + 32 * (f2 & 1) + 8 * g;
        float4 a = *reinterpret_cast<const float4*>(src);
        float4 b = *reinterpret_cast<const float4*>(src + 4);
        *reinterpret_cast<frag_ab*>(MbfF + ((size_t)f2 * 64 + lane) * 8) = cvt2(a, b);
    }
}

// -------- kernel 1: fused CCAM ----------------------------------------------
// LDS map (34816 B total):
//   [0,16640)      xbuf0: 16 rows x 260 floats (1040 B row stride, 1 KB data + pad)
//   [16640,33280)  xbuf1
//   [0,17408)      Ep[4][16][68] fp32   (overlay; live only after phase-1 loop)
//   [17408,34816)  res[w]: per-wave 16 rows x 68 floats (overlay on xbuf1 tail; phase 3 only)
__global__ __launch_bounds__(256, 4) void ccam_main(
        const float* __restrict__ x,
        const __hip_bfloat16* __restrict__ MtF,
        const __hip_bfloat16* __restrict__ MbfF,
        const float* __restrict__ aphal,
        const float* __restrict__ gamma,
        float* __restrict__ out) {
    __shared__ __align__(16) char smem[34816];
    float* xbuf[2] = { (float*)smem, (float*)(smem + 16640) };
    float (*Ep)[16][68] = (float(*)[16][68])smem;

    const int tid  = threadIdx.x;
    const int w    = tid >> 6;
    const int lane = tid & 63;
    const int g    = lane >> 4;
    const int r15  = lane & 15;
    const int rowbase = blockIdx.x * 16;
    float* resw = (float*)(smem + 17408 + w * 4352);   // 16 x 68 floats

    const float alpha = aphal[0];
    const float gam   = gamma[0];

    // ===== Phase 1: energy partials; chunked K, DMA-staged x =====
    // chunk c covers n in [256c, 256c+256); wave w computes n-slices [256c+64w, +64)
    f32x4 acc0 = {0.f, 0.f, 0.f, 0.f};
    f32x4 acc1 = acc0, acc2 = acc0, acc3 = acc0;

    // prologue: stage chunk 0 (wave stages rows 4w..4w+3, 1 KB contiguous each)
#pragma unroll
    for (int i = 0; i < 4; ++i) {
        const float* gp = x + (size_t)(rowbase + 4 * w + i) * 4096 + 0 * 256 + lane * 4;
        float* lp = xbuf[0] + (4 * w + i) * 260;
        __builtin_amdgcn_global_load_lds(AS1(gp), AS3(lp), 16, 0, 0);
    }
    __syncthreads();   // drains vmcnt(0) -> chunk 0 resident

    for (int c = 0; c < 16; ++c) {
        const float* cur = xbuf[c & 1];
        // B-frags for this chunk (contiguous 1 KB loads), BEFORE next stage so
        // the MFMA's B-wait leaves the DMA in flight.
        frag_ab B[2][4];
#pragma unroll
        for (int ks = 0; ks < 2; ++ks)
#pragma unroll
            for (int t = 0; t < 4; ++t)
                B[ks][t] = load_frag(MtF + (((size_t)(c * 8 + 2 * w + ks) * 4 + t) * 64 + lane) * 8);
        // stage chunk c+1
        if (c < 15) {
            float* nxt = xbuf[(c + 1) & 1];
#pragma unroll
            for (int i = 0; i < 4; ++i) {
                const float* gp = x + (size_t)(rowbase + 4 * w + i) * 4096 + (c + 1) * 256 + lane * 4;
                float* lp = nxt + (4 * w + i) * 260;
                __builtin_amdgcn_global_load_lds(AS1(gp), AS3(lp), 16, 0, 0);
            }
        }
        __builtin_amdgcn_sched_barrier(0);   // pin: B-loads+DMA issued above, compute below
        // compute chunk c
#pragma unroll
        for (int ks = 0; ks < 2; ++ks) {
            const float* ap = cur + r15 * 260 + 64 * w + 32 * ks + 8 * g;
            float4 a0 = *reinterpret_cast<const float4*>(ap);
            float4 a1 = *reinterpret_cast<const float4*>(ap + 4);
            frag_ab a = cvt2(a0, a1);
            acc0 = MFMA16(a, B[ks][0], acc0);
            acc1 = MFMA16(a, B[ks][1], acc1);
            acc2 = MFMA16(a, B[ks][2], acc2);
            acc3 = MFMA16(a, B[ks][3], acc3);
        }
        __syncthreads();   // vmcnt(0)+lgkmcnt(0) drain: stage done, all waves done with cur
    }

    // ===== Phase 1b: partials -> Ep (overlay on xbuf0; safe after loop barrier) =====
    // D layout: col = r15 (kdim-in-tile), row = 4g+reg (channel)
#pragma unroll
    for (int r = 0; r < 4; ++r) {
        Ep[w][4 * g + r][ 0 + r15] = acc0[r];
        Ep[w][4 * g + r][16 + r15] = acc1[r];
        Ep[w][4 * g + r][32 + r15] = acc2[r];
        Ep[w][4 * g + r][48 + r15] = acc3[r];
    }
    __syncthreads();

    // ===== Phase 2: softmax (each wave redundantly, straight into A-frag layout) =====
    float e[16];
#pragma unroll
    for (int j = 0; j < 16; ++j) e[j] = 0.f;
#pragma unroll
    for (int p = 0; p < 4; ++p) {
        float4 lo  = *reinterpret_cast<const float4*>(&Ep[p][r15][8 * g]);
        float4 lo2 = *reinterpret_cast<const float4*>(&Ep[p][r15][8 * g + 4]);
        float4 hi  = *reinterpret_cast<const float4*>(&Ep[p][r15][32 + 8 * g]);
        float4 hi2 = *reinterpret_cast<const float4*>(&Ep[p][r15][32 + 8 * g + 4]);
        e[0] += lo.x;  e[1] += lo.y;  e[2]  += lo.z;  e[3]  += lo.w;
        e[4] += lo2.x; e[5] += lo2.y; e[6]  += lo2.z; e[7]  += lo2.w;
        e[8] += hi.x;  e[9] += hi.y;  e[10] += hi.z;  e[11] += hi.w;
        e[12] += hi2.x; e[13] += hi2.y; e[14] += hi2.z; e[15] += hi2.w;
    }
    float m = e[0];
#pragma unroll
    for (int j = 1; j < 16; ++j) m = fmaxf(m, e[j]);
    m = fmaxf(m, __shfl_xor(m, 16, 64));
    m = fmaxf(m, __shfl_xor(m, 32, 64));
    float v[16];
#pragma unroll
    for (int j = 0; j < 16; ++j) v[j] = alpha * (m - e[j]);
    float vm = v[0];
#pragma unroll
    for (int j = 1; j < 16; ++j) vm = fmaxf(vm, v[j]);
    vm = fmaxf(vm, __shfl_xor(vm, 16, 64));
    vm = fmaxf(vm, __shfl_xor(vm, 32, 64));
    float pj[16];
    float s = 0.f;
#pragma unroll
    for (int j = 0; j < 16; ++j) { pj[j] = __expf(v[j] - vm); s += pj[j]; }
    s += __shfl_xor(s, 16, 64);
    s += __shfl_xor(s, 32, 64);
    const float sc = gam / s;                 // fold gamma into attention
    frag_ab A0, A1;   // row = r15 (channel), k = 8g+j (A0) / 32+8g+j (A1)
#pragma unroll
    for (int j = 0; j < 8; ++j) {
        A0[j] = (short)f2bf_bits(pj[j] * sc);
        A1[j] = (short)f2bf_bits(pj[8 + j] * sc);
    }
    __syncthreads();   // all waves done with Ep before phase 3 DMA lands near it

    // ===== Phase 3: out = (gam*att) @ M^T + x ; wave covers n in [1024w, +1024) =====
    const int nb0 = w * 1024;
    for (int grp = 0; grp < 16; ++grp) {
        const int nbase = nb0 + grp * 64;
        // 1. stage residual tile (16 rows x 64 fp32) into per-wave LDS, 256 B/instr
#pragma unroll
        for (int i = 0; i < 16; ++i) {
            const float* gp = x + (size_t)(rowbase + i) * 4096 + nbase + lane;
            float* lp = resw + i * 68;
            __builtin_amdgcn_global_load_lds(AS1(gp), AS3(lp), 4, 0, 0);
        }
        // 2. B-frags (newer than the DMAs -> B-wait implies DMA complete)
        const int nt0 = 64 * w + 4 * grp;
        frag_ab Bb[4][2];
#pragma unroll
        for (int t = 0; t < 4; ++t)
#pragma unroll
            for (int h = 0; h < 2; ++h)
                Bb[t][h] = load_frag(MbfF + (((size_t)(nt0 + t) * 2 + h) * 64 + lane) * 8);
        __builtin_amdgcn_sched_barrier(0);
        // 3. MFMA, C = 0
        f32x4 d0 = {0.f, 0.f, 0.f, 0.f};
        f32x4 d1 = d0, d2 = d0, d3 = d0;
        d0 = MFMA16(A0, Bb[0][0], d0); d0 = MFMA16(A1, Bb[0][1], d0);
        d1 = MFMA16(A0, Bb[1][0], d1); d1 = MFMA16(A1, Bb[1][1], d1);
        d2 = MFMA16(A0, Bb[2][0], d2); d2 = MFMA16(A1, Bb[2][1], d2);
        d3 = MFMA16(A0, Bb[3][0], d3); d3 = MFMA16(A1, Bb[3][1], d3);
        // 4. residual from LDS + store (insurance: DMA certainly drained, and
        //    keep the ds_reads below this point)
        asm volatile("s_waitcnt vmcnt(0)" ::: "memory");
        __builtin_amdgcn_sched_barrier(0);
#pragma unroll
        for (int r = 0; r < 4; ++r) {
            const float* rr = resw + (4 * g + r) * 68 + r15;
            float* op = out + (size_t)(rowbase + 4 * g + r) * 4096 + nbase + r15;
            op[ 0] = d0[r] + rr[ 0];
            op[16] = d1[r] + rr[16];
            op[32] = d2[r] + rr[32];
            op[48] = d3[r] + rr[48];
        }
    }
}

extern "C" void kernel_launch(void* const* d_in, const int* in_sizes, int n_in,
                              void* d_out, int out_size, void* d_ws, size_t ws_size,
                              hipStream_t stream) {
    const float* x     = (const float*)d_in[0];
    const float* M     = (const float*)d_in[1];
    const float* aphal = (const float*)d_in[2];
    const float* gamma = (const float*)d_in[3];
    __hip_bfloat16* MtF  = (__hip_bfloat16*)d_ws;                  // 512 KB
    __hip_bfloat16* MbfF = (__hip_bfloat16*)d_ws + 64 * 4096;      // 512 KB

    hipLaunchKernelGGL(prep_frags, dim3(256), dim3(256), 0, stream, M, MtF, MbfF);
    hipLaunchKernelGGL(ccam_main, dim3(1024), dim3(256), 0, stream,
                       x, MtF, MbfF, aphal, gamma, (float*)d_out);
}